// Round 5
// baseline (620.007 us; speedup 1.0000x reference)
//
#include <hip/hip_runtime.h>
#include <hip/hip_bf16.h>
#include <stdint.h>

#define DIMV 1910
#define KP   1920                 // padded K — multiple of 64
#define NT   30                   // K tiles of 64
#define PHI_F  1.6180339887498949f
#define BETA_F 0.3819660112501051f

typedef __attribute__((ext_vector_type(4))) float f32x4;
typedef __attribute__((ext_vector_type(8))) short bf16x8;
typedef __attribute__((ext_vector_type(8))) unsigned short u16x8;

__device__ __forceinline__ void gl16(const void* g, void* l) {
    __builtin_amdgcn_global_load_lds(
        (const __attribute__((address_space(1))) void*)(uintptr_t)g,
        (__attribute__((address_space(3))) void*)(uint32_t)(uintptr_t)l,
        16, 0, 0);
}

__global__ void k_scatter(const int* __restrict__ ridx, const int* __restrict__ cidx,
                          const float* __restrict__ vals, float* __restrict__ Wd, int nz) {
    int i = blockIdx.x * 256 + threadIdx.x;
    if (i < nz) atomicAdd(Wd + (long)ridx[i] * DIMV + cidx[i], vals[i]);
}

// W' = W + PHI*I, [1920 rows][1920 cols] bf16 (rows 1920..2047 of the 2048-row
// alloc stay poison: they only feed C columns >= 1920 which are never stored)
__global__ void k_build_w(const float* __restrict__ Wd, unsigned short* __restrict__ Wb, int total8) {
    int stride = gridDim.x * blockDim.x;
    for (int i = blockIdx.x * blockDim.x + threadIdx.x; i < total8; i += stride) {
        int v = i * 8;
        int n = v / KP;
        int k = v - n * KP;
        u16x8 o;
#pragma unroll
        for (int j = 0; j < 8; ++j) {
            int kk = k + j;
            float fv = (n < DIMV && kk < DIMV) ? Wd[(size_t)n * DIMV + kk] : 0.f;
            if (kk == n && n < DIMV) fv += PHI_F;
            __hip_bfloat16 b = __float2bfloat16(fv);
            o[j] = *reinterpret_cast<unsigned short*>(&b);
        }
        *(u16x8*)(Wb + (size_t)v) = o;
    }
}

// C[m][n] = BETA * sum_k A[m][k] * B[n][k];  A = x fp32 (converted in-kernel)
// Tile 256x256, BK=64, 512 threads (8 waves: 2M x 4N), per-wave 128x64.
// Persistent: grid 256 = 8 bn (XCD-pinned) x 32 bmg; each block does 4 m-tiles
// (bm = mt*32+bmg), staging the next m-tile's tile-0 during t=NT-1 so the
// epilogue overlaps staged-load latency. 4-quadrant phases, 2 LDS bufs (128KB).
// A: reg-staged fp32->bf16 (loads qd0, cvt+ds_write qd2, swizzled write addr);
// B: gl16 with pre-swizzled source (rule 21). vmcnt(0) once per tile at qd3.
__global__ __launch_bounds__(512, 2) void k_gemm(const float* __restrict__ X,
                                                 const short* __restrict__ B,
                                                 float* __restrict__ C) {
    __shared__ char lds[131072];   // 2 x (A 32KB + B 32KB)

    const int bid = blockIdx.x;
    const int bn  = bid & 7;             // XCD-pinned N column
    const int bmg = bid >> 3;            // 0..31

    const int tid = threadIdx.x;
    const int w   = tid >> 6;
    const int l   = tid & 63;
    const int wm  = w >> 2;              // 0..1 (M)
    const int wn  = w & 3;               // 0..3 (N)
    const int fr  = l & 15;
    const int q   = l >> 4;              // 0..3

    // ---- staging geometry ----
    const int    slot = tid & 7;         // logical 8-col (16B) k-slot
    const int    srow = tid >> 3;        // 0..63 row within a 64-row sweep
    const size_t KPB  = (size_t)KP * 2;  // B row bytes
    // B: pre-swizzled global source -> linear LDS dest (gl16)
    const char*  bSrc = (const char*)B + (size_t)(bn * 256 + srow) * KPB + (((tid & 7) ^ (srow & 7)) * 16);
    char* stDst = lds + tid * 16;
    // A: reg-staged; swizzled ds_write addr (logical slot -> phys slot)
    const int awOff = srow * 128 + ((slot ^ (srow & 7)) * 16);

    // ---- fragment read offsets (swizzled slots) ----
    const int co0  = ((q    ) ^ (fr & 7)) * 16;         // kk=0
    const int co1  = ((4 + q) ^ (fr & 7)) * 16;         // kk=1
    const int aOff = (wm * 128 + fr) * 128;             // + mh*8192 + mi*2048
    const int bOff = 32768 + (wn * 64 + fr) * 128;      // + nh*4096 + ni*2048

    f32x4 acc[8][4] = {};
    float2 av[4][4];                                    // staged A fp32 (32 regs)

#define STAGE_B(tt, bo, s) gl16(bSrc + (size_t)(s) * 64 * KPB + (size_t)(tt) * 128, stDst + (bo) + 32768 + (s) * 8192)

#define LOAD_A(xp, tts)                                                          \
    {                                                                            \
        const int c0 = (tts) * 64 + slot * 8;                                    \
        if (__builtin_expect((tts) != NT - 1, 1)) {                              \
            _Pragma("unroll")                                                    \
            for (int s = 0; s < 4; ++s) {                                        \
                const float* p = (xp) + (size_t)s * 64 * DIMV + c0;              \
                av[s][0] = *(const float2*)(p);                                  \
                av[s][1] = *(const float2*)(p + 2);                              \
                av[s][2] = *(const float2*)(p + 4);                              \
                av[s][3] = *(const float2*)(p + 6);                              \
            }                                                                    \
        } else {                                                                 \
            _Pragma("unroll")                                                    \
            for (int s = 0; s < 4; ++s) {                                        \
                const float* p = (xp) + (size_t)s * 64 * DIMV;                   \
                _Pragma("unroll")                                                \
                for (int j = 0; j < 4; ++j) {                                    \
                    int cp = c0 + j * 2;                                         \
                    int cc = cp < (DIMV - 2) ? cp : (DIMV - 2);                  \
                    float2 vv = *(const float2*)(p + cc);                        \
                    if (cp >= DIMV) { vv.x = 0.f; vv.y = 0.f; }                  \
                    av[s][j] = vv;                                               \
                }                                                                \
            }                                                                    \
        }                                                                        \
    }

#define WRITE_A(bo)                                                              \
    {                                                                            \
        _Pragma("unroll")                                                        \
        for (int s = 0; s < 4; ++s) {                                            \
            u16x8 o;                                                             \
            _Pragma("unroll")                                                    \
            for (int j = 0; j < 4; ++j) {                                        \
                __hip_bfloat16 b0 = __float2bfloat16(av[s][j].x);                \
                __hip_bfloat16 b1 = __float2bfloat16(av[s][j].y);                \
                o[j * 2]     = *reinterpret_cast<unsigned short*>(&b0);          \
                o[j * 2 + 1] = *reinterpret_cast<unsigned short*>(&b1);          \
            }                                                                    \
            *(u16x8*)(lds + (bo) + s * 8192 + awOff) = o;                        \
        }                                                                        \
    }

    // ---- prologue: stage (mt=0, tt=0) into buf0 ----
    {
        const float* xp0 = X + ((size_t)(bmg * 256) + srow) * DIMV;
        LOAD_A(xp0, 0)
#pragma unroll
        for (int s = 0; s < 4; ++s) STAGE_B(0, 0, s);
        WRITE_A(0)
        asm volatile("s_waitcnt vmcnt(0)" ::: "memory");
        asm volatile("s_waitcnt lgkmcnt(0)" ::: "memory");
        __builtin_amdgcn_s_barrier();
        asm volatile("" ::: "memory");
    }

    for (int mt = 0; mt < 4; ++mt) {
        const int bm = mt * 32 + bmg;
        const float* pAm = X + ((size_t)(bm * 256) + srow) * DIMV;   // this m-tile's A rows (+srow)
        int bo = 0;

        for (int t = 0; t < NT; ++t) {
            const int nbo = bo ^ 65536;
            const char* pa = lds + bo + aOff;
            const char* pb = lds + bo + bOff;
            const bool st = (mt < 3) || (t + 1 < NT);
            const int  tts = (t + 1 < NT) ? (t + 1) : 0;
            const float* xp = (t + 1 < NT) ? pAm : pAm + (size_t)8192 * DIMV;
            bf16x8 a[4][2], b[2][2];

            // ======== qd0: (mh=0, nh=0) — 12 ds_reads, issue A fp32 loads ========
#pragma unroll
            for (int mi = 0; mi < 4; ++mi) {
                a[mi][0] = *(const bf16x8*)(pa + mi * 2048 + co0);
                a[mi][1] = *(const bf16x8*)(pa + mi * 2048 + co1);
            }
#pragma unroll
            for (int ni = 0; ni < 2; ++ni) {
                b[ni][0] = *(const bf16x8*)(pb + ni * 2048 + co0);
                b[ni][1] = *(const bf16x8*)(pb + ni * 2048 + co1);
            }
            if (st) LOAD_A(xp, tts)
            asm volatile("s_waitcnt lgkmcnt(8)" ::: "memory");
            __builtin_amdgcn_s_barrier();
            asm volatile("s_waitcnt lgkmcnt(0)" ::: "memory");
            __builtin_amdgcn_sched_barrier(0);
            __builtin_amdgcn_s_setprio(1);
#pragma unroll
            for (int kk = 0; kk < 2; ++kk)
#pragma unroll
                for (int mi = 0; mi < 4; ++mi)
#pragma unroll
                    for (int ni = 0; ni < 2; ++ni)
                        acc[mi][ni] = __builtin_amdgcn_mfma_f32_16x16x32_bf16(a[mi][kk], b[ni][kk], acc[mi][ni], 0, 0, 0);
            __builtin_amdgcn_s_setprio(0);
            asm volatile("" ::: "memory");
            __builtin_amdgcn_s_barrier();
            asm volatile("" ::: "memory");

            // ======== qd1: (mh=0, nh=1) — 4 ds_reads, stage B0,B1 ========
#pragma unroll
            for (int ni = 0; ni < 2; ++ni) {
                b[ni][0] = *(const bf16x8*)(pb + 4096 + ni * 2048 + co0);
                b[ni][1] = *(const bf16x8*)(pb + 4096 + ni * 2048 + co1);
            }
            if (st) { STAGE_B(tts, nbo, 0); STAGE_B(tts, nbo, 1); }
            asm volatile("" ::: "memory");
            __builtin_amdgcn_s_barrier();
            asm volatile("s_waitcnt lgkmcnt(0)" ::: "memory");
            __builtin_amdgcn_sched_barrier(0);
            __builtin_amdgcn_s_setprio(1);
#pragma unroll
            for (int kk = 0; kk < 2; ++kk)
#pragma unroll
                for (int mi = 0; mi < 4; ++mi)
#pragma unroll
                    for (int ni = 0; ni < 2; ++ni)
                        acc[mi][ni + 2] = __builtin_amdgcn_mfma_f32_16x16x32_bf16(a[mi][kk], b[ni][kk], acc[mi][ni + 2], 0, 0, 0);
            __builtin_amdgcn_s_setprio(0);
            asm volatile("" ::: "memory");
            __builtin_amdgcn_s_barrier();
            asm volatile("" ::: "memory");

            // ======== qd2: (mh=1, nh=1) — 8 ds_reads, stage B2,B3 + A cvt/write ========
#pragma unroll
            for (int mi = 0; mi < 4; ++mi) {
                a[mi][0] = *(const bf16x8*)(pa + 8192 + mi * 2048 + co0);
                a[mi][1] = *(const bf16x8*)(pa + 8192 + mi * 2048 + co1);
            }
            if (st) {
                STAGE_B(tts, nbo, 2); STAGE_B(tts, nbo, 3);
                WRITE_A(nbo)         // compiler inserts the vmcnt for av's loads
            }
            asm volatile("" ::: "memory");
            __builtin_amdgcn_s_barrier();
            asm volatile("s_waitcnt lgkmcnt(0)" ::: "memory");
            __builtin_amdgcn_sched_barrier(0);
            __builtin_amdgcn_s_setprio(1);
#pragma unroll
            for (int kk = 0; kk < 2; ++kk)
#pragma unroll
                for (int mi = 0; mi < 4; ++mi)
#pragma unroll
                    for (int ni = 0; ni < 2; ++ni)
                        acc[mi + 4][ni + 2] = __builtin_amdgcn_mfma_f32_16x16x32_bf16(a[mi][kk], b[ni][kk], acc[mi + 4][ni + 2], 0, 0, 0);
            __builtin_amdgcn_s_setprio(0);
            asm volatile("" ::: "memory");
            __builtin_amdgcn_s_barrier();
            asm volatile("" ::: "memory");

            // ======== qd3: (mh=1, nh=0) — 4 ds_reads (B0 re-read), vmcnt after MFMA ========
#pragma unroll
            for (int ni = 0; ni < 2; ++ni) {
                b[ni][0] = *(const bf16x8*)(pb + ni * 2048 + co0);
                b[ni][1] = *(const bf16x8*)(pb + ni * 2048 + co1);
            }
            asm volatile("" ::: "memory");
            __builtin_amdgcn_s_barrier();
            asm volatile("s_waitcnt lgkmcnt(0)" ::: "memory");
            __builtin_amdgcn_sched_barrier(0);
            __builtin_amdgcn_s_setprio(1);
#pragma unroll
            for (int kk = 0; kk < 2; ++kk)
#pragma unroll
                for (int mi = 0; mi < 4; ++mi)
#pragma unroll
                    for (int ni = 0; ni < 2; ++ni)
                        acc[mi + 4][ni] = __builtin_amdgcn_mfma_f32_16x16x32_bf16(a[mi][kk], b[ni][kk], acc[mi + 4][ni], 0, 0, 0);
            __builtin_amdgcn_s_setprio(0);
            // staged B gl16s (issued qd1/qd2) must be in LDS before next qd0
            asm volatile("s_waitcnt vmcnt(0)" ::: "memory");
            __builtin_amdgcn_s_barrier();
            asm volatile("" ::: "memory");

            bo = nbo;
        }

        // ---- epilogue for this m-tile: issue stores, overlap with staged tile-0 ----
        const int grow0 = bm * 256 + wm * 128 + q * 4;
        const int gcol0 = bn * 256 + wn * 64 + fr;
#pragma unroll
        for (int ei = 0; ei < 8; ++ei) {
#pragma unroll
            for (int ni = 0; ni < 4; ++ni) {
                int gcol = gcol0 + ni * 16;
                if (gcol < DIMV) {
                    size_t base = (size_t)(grow0 + ei * 16) * DIMV + gcol;
#pragma unroll
                    for (int r = 0; r < 4; ++r)
                        C[base + (size_t)r * DIMV] = BETA_F * acc[ei][ni][r];
                }
            }
        }
        if (mt < 3) {
#pragma unroll
            for (int ei = 0; ei < 8; ++ei)
#pragma unroll
                for (int ni = 0; ni < 4; ++ni)
                    acc[ei][ni] = (f32x4)(0.f);
            asm volatile("s_waitcnt vmcnt(0)" ::: "memory");
            __builtin_amdgcn_s_barrier();
            asm volatile("" ::: "memory");
        }
    }
#undef STAGE_B
#undef LOAD_A
#undef WRITE_A
}

extern "C" void kernel_launch(void* const* d_in, const int* in_sizes, int n_in,
                              void* d_out, int out_size, void* d_ws, size_t ws_size,
                              hipStream_t stream) {
    const float* x    = (const float*)d_in[0];
    const int*   widx = (const int*)d_in[1];
    const float* wval = (const float*)d_in[2];
    float* out = (float*)d_out;

    const int nz = in_sizes[2];

    const size_t wb_bytes = (size_t)2048 * KP * 2;       // 7,864,320
    const size_t wd_bytes = (size_t)DIMV * DIMV * 4;     // 14,592,400
    char* ws = (char*)d_ws;
    unsigned short* Wb = (unsigned short*)ws;
    float*          Wd = (float*)(ws + wb_bytes);
    if (ws_size < wb_bytes + wd_bytes) return;

    hipMemsetAsync(Wd, 0, wd_bytes, stream);
    k_scatter<<<(nz + 255) / 256, 256, 0, stream>>>(widx, widx + nz, wval, Wd, nz);
    k_build_w<<<1800, 256, 0, stream>>>(Wd, Wb, KP * KP / 8);
    k_gemm<<<256, 512, 0, stream>>>(x, (const short*)Wb, out);
}

// Round 6
// 399.241 us; speedup vs baseline: 1.5530x; 1.5530x over previous
//
#include <hip/hip_runtime.h>
#include <hip/hip_bf16.h>
#include <stdint.h>

#define DIMV 1910
#define KP   1920                 // padded K — multiple of 64
#define NT   30                   // K tiles of 64
#define PHI_F  1.6180339887498949f
#define BETA_F 0.3819660112501051f

typedef __attribute__((ext_vector_type(4))) float f32x4;
typedef __attribute__((ext_vector_type(8))) short bf16x8;
typedef __attribute__((ext_vector_type(8))) unsigned short u16x8;

__device__ __forceinline__ void gl16(const void* g, void* l) {
    __builtin_amdgcn_global_load_lds(
        (const __attribute__((address_space(1))) void*)(uintptr_t)g,
        (__attribute__((address_space(3))) void*)(uint32_t)(uintptr_t)l,
        16, 0, 0);
}

// Fused prep: even blocks convert x fp32 -> bf16 [M][1920]; odd blocks scatter
// COO atomics into Wd. Conv is BW-bound, scatter atomic-latency-bound -> they
// overlap when co-resident instead of serializing as two dispatches.
__global__ void k_prep(const float* __restrict__ x, unsigned short* __restrict__ xb, int total8,
                       const int* __restrict__ ridx, const int* __restrict__ cidx,
                       const float* __restrict__ vals, float* __restrict__ Wd, int nz) {
    const int tid  = threadIdx.x;
    const int half = (int)gridDim.x >> 1;
    const int b    = (int)blockIdx.x >> 1;
    const int stride = half * 256;
    if ((blockIdx.x & 1) == 0) {
        for (int i = b * 256 + tid; i < total8; i += stride) {
            int v = i * 8;
            int row = v / KP;
            int col = v - row * KP;
            u16x8 o;
            if (col + 8 <= DIMV) {
                const float2* s = (const float2*)(x + (size_t)row * DIMV + col);
                float2 f0 = s[0], f1 = s[1], f2 = s[2], f3 = s[3];
                float f[8] = {f0.x, f0.y, f1.x, f1.y, f2.x, f2.y, f3.x, f3.y};
#pragma unroll
                for (int j = 0; j < 8; ++j) {
                    __hip_bfloat16 bb = __float2bfloat16(f[j]);
                    o[j] = *reinterpret_cast<unsigned short*>(&bb);
                }
            } else {
#pragma unroll
                for (int j = 0; j < 8; ++j) {
                    int c = col + j;
                    float fv = (c < DIMV) ? x[(size_t)row * DIMV + c] : 0.f;
                    __hip_bfloat16 bb = __float2bfloat16(fv);
                    o[j] = *reinterpret_cast<unsigned short*>(&bb);
                }
            }
            *(u16x8*)(xb + (size_t)v) = o;
        }
    } else {
        for (int i = b * 256 + tid; i < nz; i += stride)
            atomicAdd(Wd + (size_t)ridx[i] * DIMV + cidx[i], vals[i]);
    }
}

// W' = W + PHI*I, [1920 rows][1920 cols] bf16 (rows 1920..2047 of the 2048-row
// alloc stay poison: they only feed C columns >= 1920 which are never stored)
__global__ void k_build_w(const float* __restrict__ Wd, unsigned short* __restrict__ Wb, int total8) {
    int stride = gridDim.x * blockDim.x;
    for (int i = blockIdx.x * blockDim.x + threadIdx.x; i < total8; i += stride) {
        int v = i * 8;
        int n = v / KP;
        int k = v - n * KP;
        u16x8 o;
#pragma unroll
        for (int j = 0; j < 8; ++j) {
            int kk = k + j;
            float fv = (n < DIMV && kk < DIMV) ? Wd[(size_t)n * DIMV + kk] : 0.f;
            if (kk == n && n < DIMV) fv += PHI_F;
            __hip_bfloat16 b = __float2bfloat16(fv);
            o[j] = *reinterpret_cast<unsigned short*>(&b);
        }
        *(u16x8*)(Wb + (size_t)v) = o;
    }
}

// C[m][n] = BETA * sum_k A[m][k] * B[n][k];  A = xb bf16 [32768][1920]
// Tile 256x256, BK=64, 512 threads (8 waves: 2M x 4N), per-wave 128x64.
// PERSISTENT: grid 256 = 8 bn (XCD-pinned) x 32 bmg; each block loops 4 m-tiles
// (bm = mt*32+bmg). At t=NT-1 the regular stage path stages the NEXT m-tile's
// tile-0 (B panel is bn-invariant; A source advances 8192 rows), so only one
// prologue drain total and the fp32 epilogue stores (issued, NOT drained at
// the mt boundary) overlap the staged loads + next K-tile.
// 4-quadrant phases, 2 LDS bufs (128KB). gl16 with pre-swizzled source
// (rule 21): LDS row = 128B = 8 16B-slots, phys_slot = logical ^ (row&7).
__global__ __launch_bounds__(512, 2) void k_gemm(const short* __restrict__ A,
                                                 const short* __restrict__ B,
                                                 float* __restrict__ C) {
    __shared__ char lds[131072];   // 2 x (A 32KB + B 32KB)

    const int bid = blockIdx.x;
    const int bn  = bid & 7;             // XCD-pinned N column
    const int bmg = bid >> 3;            // 0..31

    const int tid = threadIdx.x;
    const int w   = tid >> 6;
    const int l   = tid & 63;
    const int wm  = w >> 2;              // 0..1 (M)
    const int wn  = w & 3;               // 0..3 (N)
    const int fr  = l & 15;
    const int q   = l >> 4;              // 0..3

    // ---- staging source (pre-swizzled), linear LDS dest ----
    const int    srow = tid >> 3;                       // row within a 64-row sweep
    const size_t KPB  = (size_t)KP * 2;                 // 3840 bytes/row
    const int    swz  = ((tid & 7) ^ (srow & 7)) * 16;
    const char*  aSrc0 = (const char*)A + (size_t)(bmg * 256 + srow) * KPB + swz;
    const char*  bSrc  = (const char*)B + (size_t)(bn * 256 + srow) * KPB + swz;
    char* stDst = lds + tid * 16;

    // ---- fragment read offsets (swizzled slots) ----
    const int co0  = ((q    ) ^ (fr & 7)) * 16;         // kk=0
    const int co1  = ((4 + q) ^ (fr & 7)) * 16;         // kk=1
    const int aOff = (wm * 128 + fr) * 128;             // + mh*8192 + mi*2048
    const int bOff = 32768 + (wn * 64 + fr) * 128;      // + nh*4096 + ni*2048

    f32x4 acc[8][4] = {};

#define STAGE_A(src, tt, bo, s) gl16((src) + (size_t)(s) * 64 * KPB + (size_t)(tt) * 128, stDst + (bo) + (s) * 8192)
#define STAGE_B(tt, bo, s)      gl16(bSrc  + (size_t)(s) * 64 * KPB + (size_t)(tt) * 128, stDst + (bo) + 32768 + (s) * 8192)

    // ---- prologue (once): stage (mt=0, t=0) into buf0 ----
#pragma unroll
    for (int s = 0; s < 4; ++s) STAGE_A(aSrc0, 0, 0, s);
#pragma unroll
    for (int s = 0; s < 4; ++s) STAGE_B(0, 0, s);
    asm volatile("s_waitcnt vmcnt(0)" ::: "memory");
    __builtin_amdgcn_s_barrier();
    asm volatile("" ::: "memory");

    for (int mt = 0; mt < 4; ++mt) {
        const char* aSrc = aSrc0 + (size_t)mt * 8192 * KPB;
        int bo = 0;

        for (int t = 0; t < NT; ++t) {
            const int nbo = bo ^ 65536;
            const char* pa = lds + bo + aOff;
            const char* pb = lds + bo + bOff;
            const bool st  = (mt < 3) || (t + 1 < NT);
            const int  tts = (t + 1 < NT) ? (t + 1) : 0;
            const char* aS = (t + 1 < NT) ? aSrc : aSrc + (size_t)8192 * KPB;  // next m-tile at t=NT-1
            bf16x8 a[4][2], b[2][2];

            // ======== qd0: (mh=0, nh=0) — 12 ds_reads, stage A0-2 ========
#pragma unroll
            for (int mi = 0; mi < 4; ++mi) {
                a[mi][0] = *(const bf16x8*)(pa + mi * 2048 + co0);
                a[mi][1] = *(const bf16x8*)(pa + mi * 2048 + co1);
            }
#pragma unroll
            for (int ni = 0; ni < 2; ++ni) {
                b[ni][0] = *(const bf16x8*)(pb + ni * 2048 + co0);
                b[ni][1] = *(const bf16x8*)(pb + ni * 2048 + co1);
            }
            if (st) { STAGE_A(aS, tts, nbo, 0); STAGE_A(aS, tts, nbo, 1); STAGE_A(aS, tts, nbo, 2); }
            asm volatile("s_waitcnt lgkmcnt(8)" ::: "memory");
            __builtin_amdgcn_s_barrier();
            asm volatile("s_waitcnt lgkmcnt(0)" ::: "memory");
            __builtin_amdgcn_sched_barrier(0);
            __builtin_amdgcn_s_setprio(1);
#pragma unroll
            for (int kk = 0; kk < 2; ++kk)
#pragma unroll
                for (int mi = 0; mi < 4; ++mi)
#pragma unroll
                    for (int ni = 0; ni < 2; ++ni)
                        acc[mi][ni] = __builtin_amdgcn_mfma_f32_16x16x32_bf16(a[mi][kk], b[ni][kk], acc[mi][ni], 0, 0, 0);
            __builtin_amdgcn_s_setprio(0);
            asm volatile("" ::: "memory");
            __builtin_amdgcn_s_barrier();
            asm volatile("" ::: "memory");

            // ======== qd1: (mh=0, nh=1) — 4 ds_reads, stage A3,B0,B1 ========
#pragma unroll
            for (int ni = 0; ni < 2; ++ni) {
                b[ni][0] = *(const bf16x8*)(pb + 4096 + ni * 2048 + co0);
                b[ni][1] = *(const bf16x8*)(pb + 4096 + ni * 2048 + co1);
            }
            if (st) { STAGE_A(aS, tts, nbo, 3); STAGE_B(tts, nbo, 0); STAGE_B(tts, nbo, 1); }
            asm volatile("" ::: "memory");
            __builtin_amdgcn_s_barrier();
            asm volatile("s_waitcnt lgkmcnt(0)" ::: "memory");
            __builtin_amdgcn_sched_barrier(0);
            __builtin_amdgcn_s_setprio(1);
#pragma unroll
            for (int kk = 0; kk < 2; ++kk)
#pragma unroll
                for (int mi = 0; mi < 4; ++mi)
#pragma unroll
                    for (int ni = 0; ni < 2; ++ni)
                        acc[mi][ni + 2] = __builtin_amdgcn_mfma_f32_16x16x32_bf16(a[mi][kk], b[ni][kk], acc[mi][ni + 2], 0, 0, 0);
            __builtin_amdgcn_s_setprio(0);
            asm volatile("" ::: "memory");
            __builtin_amdgcn_s_barrier();
            asm volatile("" ::: "memory");

            // ======== qd2: (mh=1, nh=1) — 8 ds_reads, stage B2,B3 ========
#pragma unroll
            for (int mi = 0; mi < 4; ++mi) {
                a[mi][0] = *(const bf16x8*)(pa + 8192 + mi * 2048 + co0);
                a[mi][1] = *(const bf16x8*)(pa + 8192 + mi * 2048 + co1);
            }
            if (st) { STAGE_B(tts, nbo, 2); STAGE_B(tts, nbo, 3); }
            asm volatile("" ::: "memory");
            __builtin_amdgcn_s_barrier();
            asm volatile("s_waitcnt lgkmcnt(0)" ::: "memory");
            __builtin_amdgcn_sched_barrier(0);
            __builtin_amdgcn_s_setprio(1);
#pragma unroll
            for (int kk = 0; kk < 2; ++kk)
#pragma unroll
                for (int mi = 0; mi < 4; ++mi)
#pragma unroll
                    for (int ni = 0; ni < 2; ++ni)
                        acc[mi + 4][ni + 2] = __builtin_amdgcn_mfma_f32_16x16x32_bf16(a[mi][kk], b[ni][kk], acc[mi + 4][ni + 2], 0, 0, 0);
            __builtin_amdgcn_s_setprio(0);
            asm volatile("" ::: "memory");
            __builtin_amdgcn_s_barrier();
            asm volatile("" ::: "memory");

            // ======== qd3: (mh=1, nh=0) — 4 ds_reads (B0 re-read), vmcnt after MFMA ========
#pragma unroll
            for (int ni = 0; ni < 2; ++ni) {
                b[ni][0] = *(const bf16x8*)(pb + ni * 2048 + co0);
                b[ni][1] = *(const bf16x8*)(pb + ni * 2048 + co1);
            }
            asm volatile("" ::: "memory");
            __builtin_amdgcn_s_barrier();
            asm volatile("s_waitcnt lgkmcnt(0)" ::: "memory");
            __builtin_amdgcn_sched_barrier(0);
            __builtin_amdgcn_s_setprio(1);
#pragma unroll
            for (int kk = 0; kk < 2; ++kk)
#pragma unroll
                for (int mi = 0; mi < 4; ++mi)
#pragma unroll
                    for (int ni = 0; ni < 2; ++ni)
                        acc[mi + 4][ni] = __builtin_amdgcn_mfma_f32_16x16x32_bf16(a[mi][kk], b[ni][kk], acc[mi + 4][ni], 0, 0, 0);
            __builtin_amdgcn_s_setprio(0);
            // staged gl16s for the next tile (incl. next m-tile's tile-0) must be in LDS
            asm volatile("s_waitcnt vmcnt(0)" ::: "memory");
            __builtin_amdgcn_s_barrier();
            asm volatile("" ::: "memory");

            bo = nbo;
        }

        // ---- epilogue: issue stores (NOT drained here — next tile's qd3 vmcnt
        // catches them a full K-tile later), zero acc, continue. Fast waves
        // self-synchronize at the next qd0 barrier; no extra barrier needed. ----
        const int bm    = mt * 32 + bmg;
        const int grow0 = bm * 256 + wm * 128 + q * 4;
        const int gcol0 = bn * 256 + wn * 64 + fr;
#pragma unroll
        for (int ei = 0; ei < 8; ++ei) {
#pragma unroll
            for (int ni = 0; ni < 4; ++ni) {
                int gcol = gcol0 + ni * 16;
                if (gcol < DIMV) {
                    size_t base = (size_t)(grow0 + ei * 16) * DIMV + gcol;
#pragma unroll
                    for (int r = 0; r < 4; ++r)
                        C[base + (size_t)r * DIMV] = BETA_F * acc[ei][ni][r];
                }
            }
        }
        if (mt < 3) {
#pragma unroll
            for (int ei = 0; ei < 8; ++ei)
#pragma unroll
                for (int ni = 0; ni < 4; ++ni)
                    acc[ei][ni] = (f32x4)(0.f);
        }
    }
#undef STAGE_A
#undef STAGE_B
}

extern "C" void kernel_launch(void* const* d_in, const int* in_sizes, int n_in,
                              void* d_out, int out_size, void* d_ws, size_t ws_size,
                              hipStream_t stream) {
    const float* x    = (const float*)d_in[0];
    const int*   widx = (const int*)d_in[1];
    const float* wval = (const float*)d_in[2];
    float* out = (float*)d_out;

    const int nz = in_sizes[2];
    const int M  = in_sizes[0] / DIMV;      // 32768

    const size_t xb_bytes = (size_t)M * KP * 2;          // 125,829,120
    const size_t wb_bytes = (size_t)2048 * KP * 2;       //   7,864,320
    const size_t wd_bytes = (size_t)DIMV * DIMV * 4;     //  14,592,400
    char* ws = (char*)d_ws;
    unsigned short* xb = (unsigned short*)ws;
    unsigned short* Wb = (unsigned short*)(ws + xb_bytes);
    float*          Wd = (float*)(ws + xb_bytes + wb_bytes);
    if (ws_size < xb_bytes + wb_bytes + wd_bytes) return;

    hipMemsetAsync(Wd, 0, wd_bytes, stream);
    k_prep<<<2048, 256, 0, stream>>>(x, xb, M * KP / 8, widx, widx + nz, wval, Wd, nz);
    k_build_w<<<1800, 256, 0, stream>>>(Wd, Wb, KP * KP / 8);
    k_gemm<<<256, 512, 0, stream>>>((const short*)xb, (const short*)Wb, out);
}

// Round 7
// 390.217 us; speedup vs baseline: 1.5889x; 1.0231x over previous
//
#include <hip/hip_runtime.h>
#include <hip/hip_bf16.h>
#include <stdint.h>

#define DIMV 1910
#define KP   1920                 // padded K — multiple of 64
#define NT   30                   // K tiles of 64 per m-tile
#define TT   120                  // total tiles (4 m-tiles x NT)
#define PHI_F  1.6180339887498949f
#define BETA_F 0.3819660112501051f

typedef __attribute__((ext_vector_type(4))) float f32x4;
typedef __attribute__((ext_vector_type(8))) short bf16x8;
typedef __attribute__((ext_vector_type(8))) unsigned short u16x8;

__device__ __forceinline__ void gl16(const void* g, void* l) {
    __builtin_amdgcn_global_load_lds(
        (const __attribute__((address_space(1))) void*)(uintptr_t)g,
        (__attribute__((address_space(3))) void*)(uint32_t)(uintptr_t)l,
        16, 0, 0);
}

// Fused prep: even blocks convert x fp32 -> bf16 [M][1920]; odd blocks scatter
// COO atomics into Wd (overlapped: conv is BW-bound, scatter latency-bound).
__global__ void k_prep(const float* __restrict__ x, unsigned short* __restrict__ xb, int total8,
                       const int* __restrict__ ridx, const int* __restrict__ cidx,
                       const float* __restrict__ vals, float* __restrict__ Wd, int nz) {
    const int tid  = threadIdx.x;
    const int half = (int)gridDim.x >> 1;
    const int b    = (int)blockIdx.x >> 1;
    const int stride = half * 256;
    if ((blockIdx.x & 1) == 0) {
        for (int i = b * 256 + tid; i < total8; i += stride) {
            int v = i * 8;
            int row = v / KP;
            int col = v - row * KP;
            u16x8 o;
            if (col + 8 <= DIMV) {
                const float2* s = (const float2*)(x + (size_t)row * DIMV + col);
                float2 f0 = s[0], f1 = s[1], f2 = s[2], f3 = s[3];
                float f[8] = {f0.x, f0.y, f1.x, f1.y, f2.x, f2.y, f3.x, f3.y};
#pragma unroll
                for (int j = 0; j < 8; ++j) {
                    __hip_bfloat16 bb = __float2bfloat16(f[j]);
                    o[j] = *reinterpret_cast<unsigned short*>(&bb);
                }
            } else {
#pragma unroll
                for (int j = 0; j < 8; ++j) {
                    int c = col + j;
                    float fv = (c < DIMV) ? x[(size_t)row * DIMV + c] : 0.f;
                    __hip_bfloat16 bb = __float2bfloat16(fv);
                    o[j] = *reinterpret_cast<unsigned short*>(&bb);
                }
            }
            *(u16x8*)(xb + (size_t)v) = o;
        }
    } else {
        for (int i = b * 256 + tid; i < nz; i += stride)
            atomicAdd(Wd + (size_t)ridx[i] * DIMV + cidx[i], vals[i]);
    }
}

// W' = W + PHI*I, [1920 rows][1920 cols] bf16
__global__ void k_build_w(const float* __restrict__ Wd, unsigned short* __restrict__ Wb, int total8) {
    int stride = gridDim.x * blockDim.x;
    for (int i = blockIdx.x * blockDim.x + threadIdx.x; i < total8; i += stride) {
        int v = i * 8;
        int n = v / KP;
        int k = v - n * KP;
        u16x8 o;
#pragma unroll
        for (int j = 0; j < 8; ++j) {
            int kk = k + j;
            float fv = (n < DIMV && kk < DIMV) ? Wd[(size_t)n * DIMV + kk] : 0.f;
            if (kk == n && n < DIMV) fv += PHI_F;
            __hip_bfloat16 b = __float2bfloat16(fv);
            o[j] = *reinterpret_cast<unsigned short*>(&b);
        }
        *(u16x8*)(Wb + (size_t)v) = o;
    }
}

// C[m][n] = BETA * sum_k A[m][k] * B[n][k];  A = xb bf16 [32768][1920]
// Tile 256x256, BK=64, 512 threads (8 waves: 2M x 4N), per-wave 128x64.
// PERSISTENT flat tile loop tau=0..119 (4 m-tiles x 30 K-tiles, pipeline never
// drains). A 3-deep + B 2-deep LDS buffers (160KB). Per tile: stage B(tau+1)
// in P0/P1, A(tau+2) in P1/P2 -- A issued AFTER B so vmcnt(4) at P2 drains
// A(tau+1)+B(tau+1) (+any epilogue stores) and keeps A(tau+2) in flight.
// XCD-disjoint A: bmg=bid&31, bn=bid>>5 (XCD=bid%8 -> bmg%8 fixed per XCD ->
// each XCD streams a private 1/8 of A through its own L2; B is L3-resident).
// 3 phases/tile: 12/4/8 ds_reads, 16/16/32 MFMA; b0 kept in regs (no re-read).
// Swizzle (rule 21): LDS row=128B=8 slots, phys = logical ^ (row&7), inverse
// pre-applied on the global source; verified conflict-free (r2-r6: 0 conflicts).
__global__ __launch_bounds__(512, 2) void k_gemm(const short* __restrict__ A,
                                                 const short* __restrict__ B,
                                                 float* __restrict__ C) {
    __shared__ char lds[163840];   // A: 3 x 32KB @ 0/32768/65536; B: 2 x 32KB @ 98304/131072

    const int bid = blockIdx.x;
    const int bmg = bid & 31;            // XCD-private A row group (bmg%8 == XCD)
    const int bn  = bid >> 5;            // 0..7 N column

    const int tid = threadIdx.x;
    const int w   = tid >> 6;
    const int l   = tid & 63;
    const int wm  = w >> 2;              // 0..1 (M)
    const int wn  = w & 3;               // 0..3 (N)
    const int fr  = l & 15;
    const int q   = l >> 4;              // 0..3

    // ---- staging source (pre-swizzled), linear LDS dest ----
    const int    srow = tid >> 3;                       // 0..63 row within a sweep
    const size_t KPB  = (size_t)KP * 2;                 // 3840 bytes/row
    const int    swz  = ((tid & 7) ^ (srow & 7)) * 16;
    const char*  bSrc = (const char*)B + (size_t)(bn * 256 + srow) * KPB + swz;
    const size_t sweep = (size_t)64 * KPB;
    char* stDst = lds + tid * 16;

    // ---- fragment read offsets (swizzled slots) ----
    const int co0  = ((q    ) ^ (fr & 7)) * 16;         // kk=0
    const int co1  = ((4 + q) ^ (fr & 7)) * 16;         // kk=1
    const int aOff = (wm * 128 + fr) * 128;             // + mh*8192 + mi*2048
    const int bOff = (wn * 64 + fr) * 128;              // + nh*4096 + ni*2048

    f32x4 acc[8][4] = {};

#define STAGE_A(src, kk_, dstoff, s) gl16((src) + (size_t)(s) * sweep + (size_t)(kk_) * 128, stDst + (dstoff) + (s) * 8192)
#define STAGE_B(kk_, dstoff, s)      gl16(bSrc  + (size_t)(s) * sweep + (size_t)(kk_) * 128, stDst + 98304 + (dstoff) + (s) * 8192)

    // A-source bases: read/stage row-group pointers (advance by m-tile)
    const char* aSrc0 = (const char*)A + (size_t)(bmg * 256 + srow) * KPB + swz;
    const size_t mstep = (size_t)8192 * KPB;

    // ---- prologue: A(0)->buf0, B(0)->bufB0, A(1)->buf1; keep A(1) in flight ----
#pragma unroll
    for (int s = 0; s < 4; ++s) STAGE_A(aSrc0, 0, 0, s);
#pragma unroll
    for (int s = 0; s < 4; ++s) STAGE_B(0, 0, s);
#pragma unroll
    for (int s = 0; s < 4; ++s) STAGE_A(aSrc0, 1, 32768, s);
    asm volatile("s_waitcnt vmcnt(4)" ::: "memory");
    __builtin_amdgcn_s_barrier();
    asm volatile("" ::: "memory");

    // rotating state
    int boA = 0, stA = 65536;            // A read / stage buffer offsets (mod 3)
    int boB = 0, stB = 32768;            // B read / stage buffer offsets (mod 2)
    int tkR = 0;                         // tau % 30 (read tile k-index)
    int kb1 = 1;                         // (tau+1) % 30 (B stage k-index)
    int ka2 = 2;                         // (tau+2) % 30 (A stage k-index)
    int mtR = 0;                         // read m-tile
    const char* aStage = aSrc0;          // A stage row base (m-tile of tau+2)

    for (int t = 0; t < TT; ++t) {
        const char* pa = lds + boA + aOff;
        const char* pb = lds + 98304 + boB + bOff;
        const bool stb = (t + 1 < TT);
        const bool sta = (t + 2 < TT);
        bf16x8 a[4][2], b0[2][2], b1[2][2];

        // ======== P0: 12 ds_reads (A-lo, B0), stage B(t+1) s0,s1; MFMA (mh0,nh0) ========
#pragma unroll
        for (int mi = 0; mi < 4; ++mi) {
            a[mi][0] = *(const bf16x8*)(pa + mi * 2048 + co0);
            a[mi][1] = *(const bf16x8*)(pa + mi * 2048 + co1);
        }
#pragma unroll
        for (int ni = 0; ni < 2; ++ni) {
            b0[ni][0] = *(const bf16x8*)(pb + ni * 2048 + co0);
            b0[ni][1] = *(const bf16x8*)(pb + ni * 2048 + co1);
        }
        if (stb) { STAGE_B(kb1, stB, 0); STAGE_B(kb1, stB, 1); }
        asm volatile("s_waitcnt lgkmcnt(8)" ::: "memory");
        __builtin_amdgcn_s_barrier();
        asm volatile("s_waitcnt lgkmcnt(0)" ::: "memory");
        __builtin_amdgcn_sched_barrier(0);
        __builtin_amdgcn_s_setprio(1);
#pragma unroll
        for (int kk = 0; kk < 2; ++kk)
#pragma unroll
            for (int mi = 0; mi < 4; ++mi)
#pragma unroll
                for (int ni = 0; ni < 2; ++ni)
                    acc[mi][ni] = __builtin_amdgcn_mfma_f32_16x16x32_bf16(a[mi][kk], b0[ni][kk], acc[mi][ni], 0, 0, 0);
        __builtin_amdgcn_s_setprio(0);
        asm volatile("" ::: "memory");
        __builtin_amdgcn_s_barrier();
        asm volatile("" ::: "memory");

        // ======== P1: 4 ds_reads (B1), stage B s2,s3 + A(t+2) s0,s1; MFMA (mh0,nh1) ========
#pragma unroll
        for (int ni = 0; ni < 2; ++ni) {
            b1[ni][0] = *(const bf16x8*)(pb + 4096 + ni * 2048 + co0);
            b1[ni][1] = *(const bf16x8*)(pb + 4096 + ni * 2048 + co1);
        }
        if (stb) { STAGE_B(kb1, stB, 2); STAGE_B(kb1, stB, 3); }
        if (sta) { STAGE_A(aStage, ka2, stA, 0); STAGE_A(aStage, ka2, stA, 1); }
        asm volatile("" ::: "memory");
        __builtin_amdgcn_s_barrier();
        asm volatile("s_waitcnt lgkmcnt(0)" ::: "memory");
        __builtin_amdgcn_sched_barrier(0);
        __builtin_amdgcn_s_setprio(1);
#pragma unroll
        for (int kk = 0; kk < 2; ++kk)
#pragma unroll
            for (int mi = 0; mi < 4; ++mi)
#pragma unroll
                for (int ni = 0; ni < 2; ++ni)
                    acc[mi][ni + 2] = __builtin_amdgcn_mfma_f32_16x16x32_bf16(a[mi][kk], b1[ni][kk], acc[mi][ni + 2], 0, 0, 0);
        __builtin_amdgcn_s_setprio(0);
        asm volatile("" ::: "memory");
        __builtin_amdgcn_s_barrier();
        asm volatile("" ::: "memory");

        // ======== P2: 8 ds_reads (A-hi), stage A s2,s3; MFMA (mh1,nh1)+(mh1,nh0); vmcnt ========
#pragma unroll
        for (int mi = 0; mi < 4; ++mi) {
            a[mi][0] = *(const bf16x8*)(pa + 8192 + mi * 2048 + co0);
            a[mi][1] = *(const bf16x8*)(pa + 8192 + mi * 2048 + co1);
        }
        if (sta) { STAGE_A(aStage, ka2, stA, 2); STAGE_A(aStage, ka2, stA, 3); }
        asm volatile("" ::: "memory");
        __builtin_amdgcn_s_barrier();
        asm volatile("s_waitcnt lgkmcnt(0)" ::: "memory");
        __builtin_amdgcn_sched_barrier(0);
        __builtin_amdgcn_s_setprio(1);
#pragma unroll
        for (int kk = 0; kk < 2; ++kk)
#pragma unroll
            for (int mi = 0; mi < 4; ++mi)
#pragma unroll
                for (int ni = 0; ni < 2; ++ni)
                    acc[mi + 4][ni + 2] = __builtin_amdgcn_mfma_f32_16x16x32_bf16(a[mi][kk], b1[ni][kk], acc[mi + 4][ni + 2], 0, 0, 0);
#pragma unroll
        for (int kk = 0; kk < 2; ++kk)
#pragma unroll
            for (int mi = 0; mi < 4; ++mi)
#pragma unroll
                for (int ni = 0; ni < 2; ++ni)
                    acc[mi + 4][ni] = __builtin_amdgcn_mfma_f32_16x16x32_bf16(a[mi][kk], b0[ni][kk], acc[mi + 4][ni], 0, 0, 0);
        __builtin_amdgcn_s_setprio(0);
        // drain A(t+1)+B(t+1) (and any epilogue stores); keep A(t+2) in flight
        if (sta) { asm volatile("s_waitcnt vmcnt(4)" ::: "memory"); }
        else     { asm volatile("s_waitcnt vmcnt(0)" ::: "memory"); }
        __builtin_amdgcn_s_barrier();
        asm volatile("" ::: "memory");

        // ---- epilogue at m-tile end: issue stores (drained by later vmcnt), zero acc ----
        if (tkR == NT - 1) {
            const int bm    = mtR * 32 + bmg;
            const int grow0 = bm * 256 + wm * 128 + q * 4;
            const int gcol0 = bn * 256 + wn * 64 + fr;
#pragma unroll
            for (int ei = 0; ei < 8; ++ei) {
#pragma unroll
                for (int ni = 0; ni < 4; ++ni) {
                    int gcol = gcol0 + ni * 16;
                    if (gcol < DIMV) {
                        size_t base = (size_t)(grow0 + ei * 16) * DIMV + gcol;
#pragma unroll
                        for (int r = 0; r < 4; ++r)
                            C[base + (size_t)r * DIMV] = BETA_F * acc[ei][ni][r];
                    }
                }
            }
            if (t + 1 < TT) {
#pragma unroll
                for (int ei = 0; ei < 8; ++ei)
#pragma unroll
                    for (int ni = 0; ni < 4; ++ni)
                        acc[ei][ni] = (f32x4)(0.f);
            }
            tkR = 0; ++mtR;
        } else ++tkR;

        // rotate buffers / lookahead counters
        boA = (boA == 65536) ? 0 : boA + 32768;
        stA = (stA == 65536) ? 0 : stA + 32768;
        boB ^= 32768;
        stB ^= 32768;
        if (++kb1 == NT) kb1 = 0;
        if (++ka2 == NT) { ka2 = 0; aStage += mstep; }
    }
#undef STAGE_A
#undef STAGE_B
}

extern "C" void kernel_launch(void* const* d_in, const int* in_sizes, int n_in,
                              void* d_out, int out_size, void* d_ws, size_t ws_size,
                              hipStream_t stream) {
    const float* x    = (const float*)d_in[0];
    const int*   widx = (const int*)d_in[1];
    const float* wval = (const float*)d_in[2];
    float* out = (float*)d_out;

    const int nz = in_sizes[2];
    const int M  = in_sizes[0] / DIMV;      // 32768

    const size_t xb_bytes = (size_t)M * KP * 2;          // 125,829,120
    const size_t wb_bytes = (size_t)2048 * KP * 2;       //   7,864,320
    const size_t wd_bytes = (size_t)DIMV * DIMV * 4;     //  14,592,400
    char* ws = (char*)d_ws;
    unsigned short* xb = (unsigned short*)ws;
    unsigned short* Wb = (unsigned short*)(ws + xb_bytes);
    float*          Wd = (float*)(ws + xb_bytes + wb_bytes);
    if (ws_size < xb_bytes + wb_bytes + wd_bytes) return;

    hipMemsetAsync(Wd, 0, wd_bytes, stream);
    k_prep<<<2048, 256, 0, stream>>>(x, xb, M * KP / 8, widx, widx + nz, wval, Wd, nz);
    k_build_w<<<1800, 256, 0, stream>>>(Wd, Wb, KP * KP / 8);
    k_gemm<<<256, 512, 0, stream>>>((const short*)xb, (const short*)Wb, out);
}